// Round 16
// baseline (26.902 us; speedup 1.0000x reference)
//
#include <hip/hip_runtime.h>
#include <math.h>

#define F_LEN 21
#define D_LEN 41
#define S_LEN 61                 // F_LEN + D_LEN - 1
#define ROWS 8                   // rows per block (one wave)
#define THREADS 64               // single-wave blocks
#define NELEM (ROWS * S_LEN)     // 488 float2 slots
#define NV4   (NELEM / 4)        // 122 float4 per input array
#define DOUT  (ROWS * D_LEN)     // 328 dist floats
#define DV4   (DOUT / 4)         // 82

// DPP-based add-reduce within 8-lane groups: xor1, xor2, xor7 (=half mirror).
// All VALU -- no LDS-pipe traffic (vs __shfl_xor's ds_bpermute).
// NOTE: dpp ctrl must be a compile-time immediate -> template parameter.
template <int CTRL>
__device__ __forceinline__ float dpp_add(float x) {
    int y = __builtin_amdgcn_update_dpp(0, __float_as_int(x), CTRL, 0xf, 0xf, true);
    return x + __int_as_float(y);
}
#define DPP_XOR1 0xB1            // quad_perm [1,0,3,2]
#define DPP_XOR2 0x4E            // quad_perm [2,3,0,1]
#define DPP_XOR7 0x141           // row_half_mirror (i -> 7-i == i^7 in 8-group)

// R14 base (1-wave blocks). Changes: (1) lf[21] built per-thread in
// registers via a log-depth power tree (no LDS lf table, no serial chain);
// (2) moment butterfly via DPP (no ds_bpermute). Both cut the per-CU LDS
// pipe, the co-critical resource next to HBM.
__global__ __launch_bounds__(THREADS, 4) void bp_kernel(
    const float* __restrict__ pf_g, const float* __restrict__ pb_g,
    const float* __restrict__ slop_g, const float* __restrict__ amp_g,
    float* __restrict__ out_dist, float* __restrict__ out_mean,
    float* __restrict__ out_ivar)
{
    __shared__ float2 lds_fb[NELEM];          // 3904 B; reused for dist stage

    const int tid  = threadIdx.x;
    const int rl   = tid >> 3;                // local row 0..7
    const int q    = tid & 7;                 // octant within row
    const int row0 = blockIdx.x * ROWS;
    const int r    = row0 + rl;

    // ---- staging: float4 global loads -> interleaved float2 LDS ----------
    const float4* pf4 = (const float4*)(pf_g + (size_t)row0 * S_LEN);
    const float4* pb4 = (const float4*)(pb_g + (size_t)row0 * S_LEN);
    #pragma unroll
    for (int it = 0; it < 2; ++it) {
        int idx4 = it * THREADS + tid;        // 0..127
        if (idx4 < NV4) {
            float4 f = pf4[idx4];
            float4 b = pb4[idx4];
            lds_fb[idx4 * 4 + 0] = make_float2(f.x, b.x);
            lds_fb[idx4 * 4 + 1] = make_float2(f.y, b.y);
            lds_fb[idx4 * 4 + 2] = make_float2(f.z, b.z);
            lds_fb[idx4 * 4 + 3] = make_float2(f.w, b.w);
        }
    }

    // ---- per-row scalars; lf[21] via power tree (registers only) ---------
    const float a  = amp_g[r];
    const float sl = slop_g[r];

    float lf[F_LEN];
    lf[10] = 0.5f;
    {
        const float E1 = __expf(1.0f / sl);   // e^{1/slop}, slop>=0.5
        const float E2 = E1 * E1;
        const float E4 = E2 * E2;
        const float E8 = E4 * E4;
        float Ek[11];
        Ek[1] = E1;        Ek[2] = E2;        Ek[3] = E2 * E1;
        Ek[4] = E4;        Ek[5] = E4 * E1;   Ek[6] = E4 * E2;
        Ek[7] = E4 * Ek[3];Ek[8] = E8;        Ek[9] = E8 * E1;
        Ek[10] = E8 * E2;
        #pragma unroll
        for (int k = 1; k <= 10; ++k) {
            // tanh(k/(2*slop)) = (Ek-1)/(Ek+1); no serial dependency
            float rcp = __frcp_rn(Ek[k] + 1.0f);
            float dl  = a * ((Ek[k] - 1.0f) * rcp);
            lf[10 + k] = 0.5f - dl;
            lf[10 - k] = 0.5f + dl;
        }
    }

    __syncthreads();                          // single-wave: near-free

    // ---- column-streaming product over this thread's window --------------
    const int  d0   = q * 5;
    const bool has6 = (q == 7);
    const int  base = rl * S_LEN + d0;

    float prod[6] = {1.0f, 1.0f, 1.0f, 1.0f, 1.0f, 1.0f};
    #pragma unroll
    for (int i = 0; i < 26; ++i) {            // column s = d0 + i
        float2 fb = lds_fb[base + i];         // one ds_read_b64
        float  df = fb.x - fb.y;
        #pragma unroll
        for (int dp = 0; dp < 6; ++dp) {
            const int j = i - dp;             // compile-time constant
            if (j >= 0 && j < F_LEN) {
                float t = fmaf(lf[j], df, fb.y);
                if (dp == 5) t = has6 ? t : 1.0f;
                prod[dp] *= t;
            }
        }
    }

    // ---- partial moments + 8-lane DPP butterfly --------------------------
    const float df0 = (float)d0;
    float s0 = 0.0f, s1 = 0.0f, s2 = 0.0f;
    #pragma unroll
    for (int dp = 0; dp < 6; ++dp) {
        float p = prod[dp];
        if (dp == 5) p = has6 ? p : 0.0f;
        float dv = df0 + (float)dp;
        s0 += p;
        s1 += dv * p;
        s2 += dv * dv * p;
    }
    s0 = dpp_add<DPP_XOR1>(s0); s0 = dpp_add<DPP_XOR2>(s0); s0 = dpp_add<DPP_XOR7>(s0);
    s1 = dpp_add<DPP_XOR1>(s1); s1 = dpp_add<DPP_XOR2>(s1); s1 = dpp_add<DPP_XOR7>(s1);
    s2 = dpp_add<DPP_XOR1>(s2); s2 = dpp_add<DPP_XOR2>(s2); s2 = dpp_add<DPP_XOR7>(s2);

    const float inv      = 1.0f / fmaxf(s0, 1e-12f);
    const float mean_tmp = s1 * inv;
    const float m2       = s2 * inv;
    const float var_tmp  = fmaf(-mean_tmp, mean_tmp, m2);

    if (q == 0) {
        const float two_a = 2.0f * a;
        const float at    = 0.5f * __logf((1.0f + two_a) / (1.0f - two_a));
        const float min_v = fmaxf(0.5f / (at * at), sl);
        const float var   = fmaxf(var_tmp, min_v);
        out_mean[r] = mean_tmp - (float)((D_LEN - 1) / 2);
        out_ivar[r] = 1.0f / var;
    }

    // ---- dist: stage normalized values in LDS, then float4 copy-out ------
    __syncthreads();                          // all reads of lds_fb done
    float* ldsd = (float*)lds_fb;             // alias: 328 floats needed
    #pragma unroll
    for (int dp = 0; dp < 5; ++dp)
        ldsd[rl * D_LEN + d0 + dp] = prod[dp] * inv;
    if (has6)
        ldsd[rl * D_LEN + 40] = prod[5] * inv;
    __syncthreads();

    const float4* ld4 = (const float4*)ldsd;
    float4* o4 = (float4*)(out_dist + (size_t)row0 * D_LEN);  // 16B aligned
    #pragma unroll
    for (int it = 0; it < 2; ++it) {
        int idx4 = it * THREADS + tid;        // 0..81
        if (idx4 < DV4) o4[idx4] = ld4[idx4];
    }
}

extern "C" void kernel_launch(void* const* d_in, const int* in_sizes, int n_in,
                              void* d_out, int out_size, void* d_ws, size_t ws_size,
                              hipStream_t stream) {
    // inputs: [0] lines_feature (unused), [1] pf, [2] pb, [3] slop, [4] amp
    const float* pf   = (const float*)d_in[1];
    const float* pb   = (const float*)d_in[2];
    const float* slop = (const float*)d_in[3];
    const float* amp  = (const float*)d_in[4];

    const int rows = in_sizes[3];              // B * L = 131072

    float* out_dist = (float*)d_out;
    float* out_mean = out_dist + (size_t)rows * D_LEN;
    float* out_ivar = out_mean + rows;

    const int blocks = rows / ROWS;            // 16384
    bp_kernel<<<blocks, THREADS, 0, stream>>>(pf, pb, slop, amp,
                                              out_dist, out_mean, out_ivar);
}